// Round 9
// baseline (210.440 us; speedup 1.0000x reference)
//
#include <hip/hip_runtime.h>
#include <hip/hip_bf16.h>

#define K1 195
#define K1P 224
#define K2 131
#define K2P 160
#define OC 256
#define BM 32
#define S1 232   // LDS row stride for A1 (bf16 elems): 464 B (16B-aligned rows)
#define S2 168   // LDS row stride for A2: 336 B (16B-aligned rows)

typedef __attribute__((ext_vector_type(4))) float f32x4;
typedef __attribute__((ext_vector_type(4), aligned(4))) float f32x4u;  // 4B-aligned vector load
typedef __attribute__((ext_vector_type(8))) short bf16x8;
typedef __attribute__((ext_vector_type(4))) short bf16x4;

__device__ __forceinline__ short f2b(float x) {
    __hip_bfloat16 h = __float2bfloat16(x);
    return *reinterpret_cast<short*>(&h);
}

__global__ void prep_weights_v9(const float* __restrict__ Wc, const float* __restrict__ Wa,
                                __hip_bfloat16* __restrict__ WcP, __hip_bfloat16* __restrict__ WaP) {
    int t = blockIdx.x * blockDim.x + threadIdx.x;
    const int total1 = OC * K1P;
    const int total2 = OC * K2P;
    if (t < total1) {
        int oc = t / K1P, k = t - oc * K1P;
        float v = (k < K1) ? Wc[oc * K1 + k] : 0.0f;
        WcP[t] = __float2bfloat16(v);
    } else if (t < total1 + total2) {
        int u = t - total1;
        int oc = u / K2P, k = u - oc * K2P;
        float v = (k < K2) ? Wa[oc * K2 + k] : 0.0f;
        WaP[u] = __float2bfloat16(v);
    }
}

__global__ __launch_bounds__(256) void fused_mesh_v9(
        const float* __restrict__ spatial,
        const float* __restrict__ structural,
        const int* __restrict__ neighbour,
        const __hip_bfloat16* __restrict__ WcP,
        const float* __restrict__ bc,
        const __hip_bfloat16* __restrict__ WaP,
        const float* __restrict__ ba,
        float* __restrict__ out1,
        float* __restrict__ out2,
        int n) {
    __shared__ __hip_bfloat16 A1[BM][S1];
    __shared__ __hip_bfloat16 A2[BM][S2];

    const int t = threadIdx.x;
    const int r0 = blockIdx.x * BM;

    // ---- zero-pad K tails ----
    for (int e = t; e < BM * (K1P - K1); e += 256) {
        int r = e / (K1P - K1);
        int k = K1 + (e - r * (K1P - K1));
        A1[r][k] = __float2bfloat16(0.0f);
    }
    for (int e = t; e < BM * (K2P - K2); e += 256) {
        int r = e / (K2P - K2);
        int k = K2 + (e - r * (K2P - K2));
        A2[r][k] = __float2bfloat16(0.0f);
    }

    // ---- spatial -> A1[:, 0:64] : 8 threads/row, 8 floats/thread ----
    {
        int r = t >> 3;               // 0..31
        int c0 = (t & 7) * 8;         // 0,8,..,56
        int rr = min(r0 + r, n - 1);
        const float* src = spatial + (size_t)rr * 64 + c0;
        f32x4 v0 = *(const f32x4*)src;
        f32x4 v1 = *(const f32x4*)(src + 4);
        bf16x8 o;
        #pragma unroll
        for (int j = 0; j < 4; ++j) { o[j] = f2b(v0[j]); o[4 + j] = f2b(v1[j]); }
        *(bf16x8*)&A1[r][c0] = o;
    }

    // ---- self + 3-neighbor gather, VECTORIZED: one row per thread ----
    // cols [0,128) via float4 chunks; tail cols 128..130 scalar below.
    {
        int r  = t >> 3;              // 0..31 (fixed row per thread)
        int c0 = t & 7;               // base chunk
        int rr = min(r0 + r, n - 1);
        const float* selfp = structural + (size_t)rr * K2;
        int i0 = neighbour[(size_t)rr * 3 + 0];   // L1-served (8-way redundant)
        int i1 = neighbour[(size_t)rr * 3 + 1];
        int i2 = neighbour[(size_t)rr * 3 + 2];
        const float* p0 = structural + (size_t)i0 * K2;
        const float* p1 = structural + (size_t)i1 * K2;
        const float* p2 = structural + (size_t)i2 * K2;
        #pragma unroll
        for (int i = 0; i < 4; ++i) {
            int k = (c0 + 8 * i) * 4;             // 0..124 step 4
            f32x4u vs = *(const f32x4u*)(selfp + k);
            f32x4u v0 = *(const f32x4u*)(p0 + k);
            f32x4u v1 = *(const f32x4u*)(p1 + k);
            f32x4u v2 = *(const f32x4u*)(p2 + k);
            bf16x4 s4, g4;
            #pragma unroll
            for (int j = 0; j < 4; ++j) {
                s4[j] = f2b(vs[j]);
                g4[j] = f2b((vs[j] + v0[j] + v1[j] + v2[j]) * 0.25f);
            }
            *(bf16x4*)&A1[r][64 + k] = s4;        // byte off 128+8k' -> 8B aligned
            *(bf16x4*)&A2[r][k]      = g4;        // 8B aligned
        }
    }
    // tail cols 128..130 : 96 threads, one (row,col) each
    if (t < 96) {
        int r  = t / 3;
        int k  = 128 + (t - r * 3);
        int rr = min(r0 + r, n - 1);
        float self = structural[(size_t)rr * K2 + k];
        int i0 = neighbour[(size_t)rr * 3 + 0];
        int i1 = neighbour[(size_t)rr * 3 + 1];
        int i2 = neighbour[(size_t)rr * 3 + 2];
        float v = self + structural[(size_t)i0 * K2 + k]
                       + structural[(size_t)i1 * K2 + k]
                       + structural[(size_t)i2 * K2 + k];
        A1[r][64 + k] = __float2bfloat16(self);
        A2[r][k]      = __float2bfloat16(v * 0.25f);
    }
    __syncthreads();  // single barrier: all staging done

    // ---- MFMA GEMMs, swapped operands (A=weights, B=nodes) ----
    const int wid  = t >> 6;
    const int lane = t & 63;
    const int lr   = lane & 15;
    const int lkc  = lane >> 4;
    const int colBase = wid * 64;

    // ---- GEMM 1: out1 = A1 * WcP^T + bc ----
    {
        f32x4 acc[4][2];  // [ct = oc tile][rt = node tile]
        #pragma unroll
        for (int i = 0; i < 4; ++i)
            #pragma unroll
            for (int j = 0; j < 2; ++j)
                acc[i][j] = (f32x4){0.f, 0.f, 0.f, 0.f};

        #pragma unroll
        for (int ks = 0; ks < K1P; ks += 32) {
            bf16x8 a[2], b[4];
            #pragma unroll
            for (int rt = 0; rt < 2; ++rt)
                a[rt] = *(const bf16x8*)&A1[rt * 16 + lr][ks + lkc * 8];
            #pragma unroll
            for (int ct = 0; ct < 4; ++ct) {
                int oc = colBase + ct * 16 + lr;
                b[ct] = *(const bf16x8*)(WcP + (size_t)oc * K1P + ks + lkc * 8);
            }
            #pragma unroll
            for (int rt = 0; rt < 2; ++rt)
                #pragma unroll
                for (int ct = 0; ct < 4; ++ct)
                    acc[ct][rt] = __builtin_amdgcn_mfma_f32_16x16x32_bf16(b[ct], a[rt], acc[ct][rt], 0, 0, 0);
        }

        #pragma unroll
        for (int ct = 0; ct < 4; ++ct) {
            int oc0 = colBase + ct * 16 + lkc * 4;
            f32x4 b4 = *(const f32x4*)(bc + oc0);
            #pragma unroll
            for (int rt = 0; rt < 2; ++rt) {
                int node = r0 + rt * 16 + lr;
                if (node < n) {
                    f32x4 v = acc[ct][rt] + b4;
                    __builtin_nontemporal_store(v, (f32x4*)(out1 + (size_t)node * OC + oc0));
                }
            }
        }
    }

    // ---- GEMM 2: out2 = A2 * WaP^T + ba ----
    {
        f32x4 acc[4][2];
        #pragma unroll
        for (int i = 0; i < 4; ++i)
            #pragma unroll
            for (int j = 0; j < 2; ++j)
                acc[i][j] = (f32x4){0.f, 0.f, 0.f, 0.f};

        #pragma unroll
        for (int ks = 0; ks < K2P; ks += 32) {
            bf16x8 a[2], b[4];
            #pragma unroll
            for (int rt = 0; rt < 2; ++rt)
                a[rt] = *(const bf16x8*)&A2[rt * 16 + lr][ks + lkc * 8];
            #pragma unroll
            for (int ct = 0; ct < 4; ++ct) {
                int oc = colBase + ct * 16 + lr;
                b[ct] = *(const bf16x8*)(WaP + (size_t)oc * K2P + ks + lkc * 8);
            }
            #pragma unroll
            for (int rt = 0; rt < 2; ++rt)
                #pragma unroll
                for (int ct = 0; ct < 4; ++ct)
                    acc[ct][rt] = __builtin_amdgcn_mfma_f32_16x16x32_bf16(b[ct], a[rt], acc[ct][rt], 0, 0, 0);
        }

        #pragma unroll
        for (int ct = 0; ct < 4; ++ct) {
            int oc0 = colBase + ct * 16 + lkc * 4;
            f32x4 b4 = *(const f32x4*)(ba + oc0);
            #pragma unroll
            for (int rt = 0; rt < 2; ++rt) {
                int node = r0 + rt * 16 + lr;
                if (node < n) {
                    f32x4 v = acc[ct][rt] + b4;
                    __builtin_nontemporal_store(v, (f32x4*)(out2 + (size_t)node * OC + oc0));
                }
            }
        }
    }
}

extern "C" void kernel_launch(void* const* d_in, const int* in_sizes, int n_in,
                              void* d_out, int out_size, void* d_ws, size_t ws_size,
                              hipStream_t stream) {
    const float* spatial    = (const float*)d_in[0];
    const float* structural = (const float*)d_in[1];
    const int*   neighbour  = (const int*)d_in[2];
    const float* Wc = (const float*)d_in[3];
    const float* bc = (const float*)d_in[4];
    const float* Wa = (const float*)d_in[5];
    const float* ba = (const float*)d_in[6];

    const int n = in_sizes[0] / 64;  // 200000

    float* out1 = (float*)d_out;
    float* out2 = out1 + (size_t)n * OC;

    __hip_bfloat16* WcP = (__hip_bfloat16*)d_ws;
    __hip_bfloat16* WaP = WcP + OC * K1P;

    {
        const int total = OC * K1P + OC * K2P;
        prep_weights_v9<<<(total + 255) / 256, 256, 0, stream>>>(Wc, Wa, WcP, WaP);
    }
    {
        const int grid = (n + BM - 1) / BM;  // 6250
        fused_mesh_v9<<<grid, 256, 0, stream>>>(spatial, structural, neighbour,
                                                WcP, bc, WaP, ba, out1, out2, n);
    }
}

// Round 11
// 192.148 us; speedup vs baseline: 1.0952x; 1.0952x over previous
//
#include <hip/hip_runtime.h>
#include <hip/hip_bf16.h>

#define K1 195
#define K1P 224
#define K2 131
#define K2P 160
#define OC 256
#define BM 32
#define S1 232   // LDS row stride A1 (bf16): 464 B; rows 16B-aligned (232=29*8)
#define S2 168   // LDS row stride A2 (bf16): 336 B; rows 16B-aligned (168=21*8)
#define THREADS 512

typedef __attribute__((ext_vector_type(4))) float f32x4;
typedef __attribute__((ext_vector_type(8))) short bf16x8;
typedef __attribute__((ext_vector_type(4))) short bf16x4;

__device__ __forceinline__ short f2b(float x) {
    __hip_bfloat16 h = __float2bfloat16(x);
    return *reinterpret_cast<short*>(&h);
}

__global__ void prep_weights_v11(const float* __restrict__ Wc, const float* __restrict__ Wa,
                                 __hip_bfloat16* __restrict__ WcP, __hip_bfloat16* __restrict__ WaP) {
    int t = blockIdx.x * blockDim.x + threadIdx.x;
    const int total1 = OC * K1P;
    const int total2 = OC * K2P;
    if (t < total1) {
        int oc = t / K1P, k = t - oc * K1P;
        float v = (k < K1) ? Wc[oc * K1 + k] : 0.0f;
        WcP[t] = __float2bfloat16(v);
    } else if (t < total1 + total2) {
        int u = t - total1;
        int oc = u / K2P, k = u - oc * K2P;
        float v = (k < K2) ? Wa[oc * K2 + k] : 0.0f;
        WaP[u] = __float2bfloat16(v);
    }
}

__global__ __launch_bounds__(THREADS) void fused_mesh_v11(
        const float* __restrict__ spatial,
        const float* __restrict__ structural,
        const int* __restrict__ neighbour,
        const __hip_bfloat16* __restrict__ WcP,
        const float* __restrict__ bc,
        const __hip_bfloat16* __restrict__ WaP,
        const float* __restrict__ ba,
        float* __restrict__ out1,
        float* __restrict__ out2,
        int n) {
    __shared__ __hip_bfloat16 A1[BM][S1];
    __shared__ __hip_bfloat16 A2[BM][S2];
    __shared__ int nidx[BM * 3];

    const int t = threadIdx.x;
    const int r0 = blockIdx.x * BM;

    // ---- stage neighbour indices ----
    if (t < BM * 3) {
        size_t gi = (size_t)r0 * 3 + t;
        nidx[t] = (gi < (size_t)n * 3) ? neighbour[gi] : 0;
    }

    // ---- zero-pad K tails ----
    for (int e = t; e < BM * (K1P - K1); e += THREADS) {
        int r = e / (K1P - K1);
        int k = K1 + (e - r * (K1P - K1));
        A1[r][k] = __float2bfloat16(0.0f);
    }
    for (int e = t; e < BM * (K2P - K2); e += THREADS) {
        int r = e / (K2P - K2);
        int k = K2 + (e - r * (K2P - K2));
        A2[r][k] = __float2bfloat16(0.0f);
    }

    // ---- spatial -> A1[:, 0:64] : 16 threads/row, 4 floats/thread ----
    {
        int r  = t >> 4;              // 0..31
        int c0 = (t & 15) * 4;        // 0,4,..,60
        int rr = min(r0 + r, n - 1);
        f32x4 v = *(const f32x4*)(spatial + (size_t)rr * 64 + c0);
        bf16x4 o;
        #pragma unroll
        for (int j = 0; j < 4; ++j) o[j] = f2b(v[j]);
        *(bf16x4*)&A1[r][c0] = o;    // c0*2 bytes -> 8B aligned
    }
    __syncthreads();  // nidx ready

    // ---- structural self + gather -> A1[:,64:195], A2[:,0:131] (R8 loop, 512-stride) ----
    for (int e = t; e < BM * K2; e += THREADS) {
        int r = e / K2;
        int k = e - r * K2;
        int rr = min(r0 + r, n - 1);
        float self = structural[(size_t)rr * K2 + k];
        int n0 = nidx[r * 3 + 0];
        int n1 = nidx[r * 3 + 1];
        int n2 = nidx[r * 3 + 2];
        float v = self + structural[(size_t)n0 * K2 + k]
                       + structural[(size_t)n1 * K2 + k]
                       + structural[(size_t)n2 * K2 + k];
        A1[r][64 + k] = __float2bfloat16(self);
        A2[r][k]      = __float2bfloat16(v * 0.25f);
    }
    __syncthreads();

    // ---- MFMA GEMMs, swapped operands (A=weights, B=nodes) ----
    // 8 waves; wave w owns oc cols [w*32, w*32+32) x all 32 nodes.
    // D layout: col(lane&15)=node, row((lane>>4)*4+j)=oc -> 4 consecutive oc
    // per lane -> one nontemporal dwordx4 store per fragment.
    const int wid  = t >> 6;          // 0..7
    const int lane = t & 63;
    const int lr   = lane & 15;
    const int lkc  = lane >> 4;
    const int colBase = wid * 32;

    // ---- GEMM 1: out1 = A1 * WcP^T + bc ----
    {
        f32x4 acc[2][2];  // [ct = oc tile][rt = node tile]
        #pragma unroll
        for (int i = 0; i < 2; ++i)
            #pragma unroll
            for (int j = 0; j < 2; ++j)
                acc[i][j] = (f32x4){0.f, 0.f, 0.f, 0.f};

        #pragma unroll
        for (int ks = 0; ks < K1P; ks += 32) {
            bf16x8 a[2], b[2];
            #pragma unroll
            for (int rt = 0; rt < 2; ++rt)
                a[rt] = *(const bf16x8*)&A1[rt * 16 + lr][ks + lkc * 8];
            #pragma unroll
            for (int ct = 0; ct < 2; ++ct) {
                int oc = colBase + ct * 16 + lr;
                b[ct] = *(const bf16x8*)(WcP + (size_t)oc * K1P + ks + lkc * 8);
            }
            #pragma unroll
            for (int rt = 0; rt < 2; ++rt)
                #pragma unroll
                for (int ct = 0; ct < 2; ++ct)
                    acc[ct][rt] = __builtin_amdgcn_mfma_f32_16x16x32_bf16(b[ct], a[rt], acc[ct][rt], 0, 0, 0);
        }

        #pragma unroll
        for (int ct = 0; ct < 2; ++ct) {
            int oc0 = colBase + ct * 16 + lkc * 4;
            f32x4 b4 = *(const f32x4*)(bc + oc0);
            #pragma unroll
            for (int rt = 0; rt < 2; ++rt) {
                int node = r0 + rt * 16 + lr;
                if (node < n) {
                    f32x4 v = acc[ct][rt] + b4;
                    __builtin_nontemporal_store(v, (f32x4*)(out1 + (size_t)node * OC + oc0));
                }
            }
        }
    }

    // ---- GEMM 2: out2 = A2 * WaP^T + ba ----
    {
        f32x4 acc[2][2];
        #pragma unroll
        for (int i = 0; i < 2; ++i)
            #pragma unroll
            for (int j = 0; j < 2; ++j)
                acc[i][j] = (f32x4){0.f, 0.f, 0.f, 0.f};

        #pragma unroll
        for (int ks = 0; ks < K2P; ks += 32) {
            bf16x8 a[2], b[2];
            #pragma unroll
            for (int rt = 0; rt < 2; ++rt)
                a[rt] = *(const bf16x8*)&A2[rt * 16 + lr][ks + lkc * 8];
            #pragma unroll
            for (int ct = 0; ct < 2; ++ct) {
                int oc = colBase + ct * 16 + lr;
                b[ct] = *(const bf16x8*)(WaP + (size_t)oc * K2P + ks + lkc * 8);
            }
            #pragma unroll
            for (int rt = 0; rt < 2; ++rt)
                #pragma unroll
                for (int ct = 0; ct < 2; ++ct)
                    acc[ct][rt] = __builtin_amdgcn_mfma_f32_16x16x32_bf16(b[ct], a[rt], acc[ct][rt], 0, 0, 0);
        }

        #pragma unroll
        for (int ct = 0; ct < 2; ++ct) {
            int oc0 = colBase + ct * 16 + lkc * 4;
            f32x4 b4 = *(const f32x4*)(ba + oc0);
            #pragma unroll
            for (int rt = 0; rt < 2; ++rt) {
                int node = r0 + rt * 16 + lr;
                if (node < n) {
                    f32x4 v = acc[ct][rt] + b4;
                    __builtin_nontemporal_store(v, (f32x4*)(out2 + (size_t)node * OC + oc0));
                }
            }
        }
    }
}

extern "C" void kernel_launch(void* const* d_in, const int* in_sizes, int n_in,
                              void* d_out, int out_size, void* d_ws, size_t ws_size,
                              hipStream_t stream) {
    const float* spatial    = (const float*)d_in[0];
    const float* structural = (const float*)d_in[1];
    const int*   neighbour  = (const int*)d_in[2];
    const float* Wc = (const float*)d_in[3];
    const float* bc = (const float*)d_in[4];
    const float* Wa = (const float*)d_in[5];
    const float* ba = (const float*)d_in[6];

    const int n = in_sizes[0] / 64;  // 200000

    float* out1 = (float*)d_out;
    float* out2 = out1 + (size_t)n * OC;

    __hip_bfloat16* WcP = (__hip_bfloat16*)d_ws;
    __hip_bfloat16* WaP = WcP + OC * K1P;

    {
        const int total = OC * K1P + OC * K2P;
        prep_weights_v11<<<(total + 255) / 256, 256, 0, stream>>>(Wc, Wa, WcP, WaP);
    }
    {
        const int grid = (n + BM - 1) / BM;  // 6250
        fused_mesh_v11<<<grid, THREADS, 0, stream>>>(spatial, structural, neighbour,
                                                     WcP, bc, WaP, ba, out1, out2, n);
    }
}